// Round 10
// baseline (316.513 us; speedup 1.0000x reference)
//
#include <hip/hip_runtime.h>
#include <math.h>

#define B_ 2
#define S_ 2048
#define D_ 1024
#define H_ 16
#define HD 64
#define M_ (B_ * S_)     // 4096
#define N_QKV (3 * D_)   // 3072

typedef short short8 __attribute__((ext_vector_type(8)));
typedef float floatx4 __attribute__((ext_vector_type(4)));

static __device__ __forceinline__ unsigned short f2bf_rne(float x) {
    union { float f; unsigned u; } v; v.f = x;
    unsigned r = v.u + 0x7FFFu + ((v.u >> 16) & 1u);
    return (unsigned short)(r >> 16);
}
static __device__ __forceinline__ float bf2f(unsigned short b) {
    union { unsigned u; float f; } v; v.u = ((unsigned)b) << 16;
    return v.f;
}
// RNE split: x = hi + lo + eps, |eps| ~ 2^-17 |x|
static __device__ __forceinline__ void split2(float x, unsigned short& h, unsigned short& l) {
    h = f2bf_rne(x);
    l = f2bf_rne(x - bf2f(h));
}

// async global->LDS DMA, 16 B per lane (dest = wave-uniform base + lane*16)
static __device__ __forceinline__ void dma16(const void* g, void* l) {
    __builtin_amdgcn_global_load_lds(
        (const __attribute__((address_space(1))) unsigned int*)g,
        (__attribute__((address_space(3))) unsigned int*)l,
        16, 0, 0);
}

// ---------------------------------------------------------------------------
// prep_hs: hs fp32 [4096,1024] -> pre-split bf16 hi/lo (stored in d_out,
// which is scratch until gemm_out overwrites it). ~34 MB traffic, ~6 us.
// ---------------------------------------------------------------------------
__global__ __launch_bounds__(256) void prep_hs(
    const float* __restrict__ A,
    unsigned short* __restrict__ Ahi, unsigned short* __restrict__ Alo)
{
    const size_t i = ((size_t)blockIdx.x * 256 + threadIdx.x) * 8;
    float4 v0 = *(const float4*)(A + i);
    float4 v1 = *(const float4*)(A + i + 4);
    float xs[8] = {v0.x, v0.y, v0.z, v0.w, v1.x, v1.y, v1.z, v1.w};
    short8 h, l;
#pragma unroll
    for (int j = 0; j < 8; j++) {
        unsigned short hh, ll;
        split2(xs[j], hh, ll);
        h[j] = (short)hh; l[j] = (short)ll;
    }
    *(short8*)&Ahi[i] = h;
    *(short8*)&Alo[i] = l;
}

// ---------------------------------------------------------------------------
// prep_wT: W[K=1024][N] fp32 -> WT hi/lo bf16 [N][1024]. (R7-R9-verified)
// ---------------------------------------------------------------------------
__global__ __launch_bounds__(256) void prep_wT(
    const float* __restrict__ W, int N,
    unsigned short* __restrict__ Thi, unsigned short* __restrict__ Tlo)
{
    __shared__ float Ws[64][68];
    const int t  = threadIdx.x;
    const int n0 = blockIdx.x * 64, k0 = blockIdx.y * 64;
    {
        const int kl = t >> 4, nl = (t & 15) * 4;
        const float* src = W + (size_t)(k0 + kl) * N + n0 + nl;
#pragma unroll
        for (int g = 0; g < 4; g++)
            *(float4*)&Ws[kl + g * 16][nl] = *(const float4*)(src + (size_t)g * 16 * N);
    }
    __syncthreads();
    {
        const int nl = t >> 2, ks = (t & 3) * 16;
        short8 h0, h1, l0, l1;
#pragma unroll
        for (int j = 0; j < 8; j++) {
            unsigned short hh, ll;
            split2(Ws[ks + j][nl], hh, ll);
            h0[j] = (short)hh; l0[j] = (short)ll;
        }
#pragma unroll
        for (int j = 0; j < 8; j++) {
            unsigned short hh, ll;
            split2(Ws[ks + 8 + j][nl], hh, ll);
            h1[j] = (short)hh; l1[j] = (short)ll;
        }
        unsigned short* dh = Thi + (size_t)(n0 + nl) * D_ + k0 + ks;
        unsigned short* dl = Tlo + (size_t)(n0 + nl) * D_ + k0 + ks;
        *(short8*)dh = h0; *(short8*)(dh + 8) = h1;
        *(short8*)dl = l0; *(short8*)(dl + 8) = l1;
    }
}

// ---------------------------------------------------------------------------
// QKV GEMM: both A (pre-split hs) and B (pre-split W^T) staged via
// global_load_lds DMA -- ZERO VALU / ds_write in the K-loop (gemm_out-shape,
// R8-verified, but 48 MFMA/wave/iter amortizing the barriers).
// Epilogue writes pre-split Q*(1/8), K [s][d], V^T [b][h][d][s].
// ---------------------------------------------------------------------------
__global__ __launch_bounds__(256) void gemm_qkv(
    const unsigned short* __restrict__ Ahi, const unsigned short* __restrict__ Alo,
    const unsigned short* __restrict__ BThi, const unsigned short* __restrict__ BTlo,
    const float* __restrict__ bias,
    unsigned short* __restrict__ Qhi, unsigned short* __restrict__ Qlo,
    unsigned short* __restrict__ Khi, unsigned short* __restrict__ Klo,
    unsigned short* __restrict__ vThi, unsigned short* __restrict__ vTlo)
{
    __shared__ unsigned short sAh[128 * 32], sAl[128 * 32];
    __shared__ unsigned short sBh[128 * 32], sBl[128 * 32];

    const int t    = threadIdx.x;
    const int m0   = blockIdx.y * 128, n0 = blockIdx.x * 128;
    const int lane = t & 63, wave = t >> 6;
    const int lm   = lane & 15, quad = lane >> 4;
    const int wm   = (wave >> 1) * 64, wn = (wave & 1) * 64;

    // DMA maps: wave covers 32 rows (2 instrs of 16 rows), lane -> row lrow,
    // 16-B col chunk lcol.
    const int lrow = lane >> 2, lcol = (lane & 3) * 8;
    const unsigned short* gAh0 = Ahi + (size_t)(m0 + wave * 32 + lrow) * D_ + lcol;
    const unsigned short* gAl0 = Alo + (size_t)(m0 + wave * 32 + lrow) * D_ + lcol;
    const unsigned short* gBh0 = BThi + (size_t)(n0 + wave * 32 + lrow) * D_ + lcol;
    const unsigned short* gBl0 = BTlo + (size_t)(n0 + wave * 32 + lrow) * D_ + lcol;
    unsigned short* lAh0 = sAh + wave * 1024 + lane * 8;
    unsigned short* lAl0 = sAl + wave * 1024 + lane * 8;
    unsigned short* lBh0 = sBh + wave * 1024 + lane * 8;
    unsigned short* lBl0 = sBl + wave * 1024 + lane * 8;

    floatx4 acc[4][4];
#pragma unroll
    for (int i = 0; i < 4; i++)
#pragma unroll
        for (int j = 0; j < 4; j++)
#pragma unroll
            for (int r = 0; r < 4; r++) acc[i][j][r] = 0.f;

    for (int k0 = 0; k0 < D_; k0 += 32) {
        __syncthreads();   // previous tile's consumers done
        dma16(gAh0 + k0, lAh0);
        dma16(gAh0 + (size_t)16 * D_ + k0, lAh0 + 512);
        dma16(gAl0 + k0, lAl0);
        dma16(gAl0 + (size_t)16 * D_ + k0, lAl0 + 512);
        dma16(gBh0 + k0, lBh0);
        dma16(gBh0 + (size_t)16 * D_ + k0, lBh0 + 512);
        dma16(gBl0 + k0, lBl0);
        dma16(gBl0 + (size_t)16 * D_ + k0, lBl0 + 512);
        __syncthreads();   // vmcnt+lgkm drained: tile staged

        short8 bhf[4], blf[4];
#pragma unroll
        for (int nb = 0; nb < 4; nb++) {
            const int r = wn + nb * 16 + lm;
            bhf[nb] = *(const short8*)&sBh[r * 32 + quad * 8];
            blf[nb] = *(const short8*)&sBl[r * 32 + quad * 8];
        }
#pragma unroll
        for (int mb = 0; mb < 4; mb++) {
            const int r = wm + mb * 16 + lm;
            short8 ah = *(const short8*)&sAh[r * 32 + quad * 8];
            short8 al = *(const short8*)&sAl[r * 32 + quad * 8];
#pragma unroll
            for (int nb = 0; nb < 4; nb++) {
                acc[mb][nb] = __builtin_amdgcn_mfma_f32_16x16x32_bf16(ah, bhf[nb], acc[mb][nb], 0, 0, 0);
                acc[mb][nb] = __builtin_amdgcn_mfma_f32_16x16x32_bf16(al, bhf[nb], acc[mb][nb], 0, 0, 0);
                acc[mb][nb] = __builtin_amdgcn_mfma_f32_16x16x32_bf16(ah, blf[nb], acc[mb][nb], 0, 0, 0);
            }
        }
    }

    const int nmode = n0 >> 10;   // 0=Q, 1=K, 2=V (block-uniform)
    if (nmode == 0) {
#pragma unroll
        for (int nb = 0; nb < 4; nb++) {
            const int c = n0 + wn + nb * 16 + lm;
            const float bv = bias[c];
#pragma unroll
            for (int mb = 0; mb < 4; mb++) {
                const int rowb = m0 + wm + mb * 16 + quad * 4;
#pragma unroll
                for (int r = 0; r < 4; r++) {
                    unsigned short hh, ll;
                    split2((acc[mb][nb][r] + bv) * 0.125f, hh, ll);
                    Qhi[(size_t)(rowb + r) * D_ + c] = hh;
                    Qlo[(size_t)(rowb + r) * D_ + c] = ll;
                }
            }
        }
    } else if (nmode == 1) {
#pragma unroll
        for (int nb = 0; nb < 4; nb++) {
            const int c = n0 + wn + nb * 16 + lm;
            const float bv = bias[c];
            const int cq = c - 1024;
#pragma unroll
            for (int mb = 0; mb < 4; mb++) {
                const int rowb = m0 + wm + mb * 16 + quad * 4;
#pragma unroll
                for (int r = 0; r < 4; r++) {
                    unsigned short hh, ll;
                    split2(acc[mb][nb][r] + bv, hh, ll);
                    Khi[(size_t)(rowb + r) * D_ + cq] = hh;
                    Klo[(size_t)(rowb + r) * D_ + cq] = ll;
                }
            }
        }
    } else {
#pragma unroll
        for (int nb = 0; nb < 4; nb++) {
            const int c = n0 + wn + nb * 16 + lm;
            const float bv = bias[c];
            const int cq = c - 2048;
            const int hh_ = cq >> 6, dd = cq & 63;
#pragma unroll
            for (int mb = 0; mb < 4; mb++) {
                const int rowb = m0 + wm + mb * 16 + quad * 4;
                const int bb = rowb >> 11, ss = rowb & 2047;
                unsigned short hv[4], lv[4];
#pragma unroll
                for (int r = 0; r < 4; r++)
                    split2(acc[mb][nb][r] + bv, hv[r], lv[r]);
                const size_t idx = ((size_t)((bb * 16 + hh_) * 64 + dd)) * S_ + ss;
                *(uint2*)&vThi[idx] = make_uint2((unsigned)hv[0] | ((unsigned)hv[1] << 16),
                                                 (unsigned)hv[2] | ((unsigned)hv[3] << 16));
                *(uint2*)&vTlo[idx] = make_uint2((unsigned)lv[0] | ((unsigned)lv[1] << 16),
                                                 (unsigned)lv[2] | ((unsigned)lv[3] << 16));
            }
        }
    }
}

// ---------------------------------------------------------------------------
// Proj GEMM (R8/R9-verified): 64x64 tiles, fully-DMA staging, zero K-loop VALU.
// ---------------------------------------------------------------------------
__global__ __launch_bounds__(256) void gemm_out(
    const unsigned short* __restrict__ Ahi, const unsigned short* __restrict__ Alo,
    const unsigned short* __restrict__ BThi, const unsigned short* __restrict__ BTlo,
    const float* __restrict__ bias, float* __restrict__ C)
{
    __shared__ unsigned short sAh[64 * 32], sAl[64 * 32];
    __shared__ unsigned short sBh[64 * 32], sBl[64 * 32];

    const int t    = threadIdx.x;
    const int m0   = blockIdx.y * 64, n0 = blockIdx.x * 64;
    const int lane = t & 63, wave = t >> 6;
    const int lm   = lane & 15, quad = lane >> 4;

    const int lrow = lane >> 2, lcol = (lane & 3) * 8;
    const unsigned short* gAh = Ahi + (size_t)(m0 + wave * 16 + lrow) * D_ + lcol;
    const unsigned short* gAl = Alo + (size_t)(m0 + wave * 16 + lrow) * D_ + lcol;
    const unsigned short* gBh = BThi + (size_t)(n0 + wave * 16 + lrow) * D_ + lcol;
    const unsigned short* gBl = BTlo + (size_t)(n0 + wave * 16 + lrow) * D_ + lcol;
    unsigned short* lAh = sAh + wave * 512 + lane * 8;
    unsigned short* lAl = sAl + wave * 512 + lane * 8;
    unsigned short* lBh = sBh + wave * 512 + lane * 8;
    unsigned short* lBl = sBl + wave * 512 + lane * 8;

    floatx4 acc[4];
#pragma unroll
    for (int j = 0; j < 4; j++)
#pragma unroll
        for (int r = 0; r < 4; r++) acc[j][r] = 0.f;

    for (int k0 = 0; k0 < D_; k0 += 32) {
        __syncthreads();
        dma16(gAh + k0, lAh);
        dma16(gAl + k0, lAl);
        dma16(gBh + k0, lBh);
        dma16(gBl + k0, lBl);
        __syncthreads();

        short8 ah = *(const short8*)&sAh[(wave * 16 + lm) * 32 + quad * 8];
        short8 al = *(const short8*)&sAl[(wave * 16 + lm) * 32 + quad * 8];
#pragma unroll
        for (int nb = 0; nb < 4; nb++) {
            short8 bh = *(const short8*)&sBh[(nb * 16 + lm) * 32 + quad * 8];
            short8 bl = *(const short8*)&sBl[(nb * 16 + lm) * 32 + quad * 8];
            acc[nb] = __builtin_amdgcn_mfma_f32_16x16x32_bf16(ah, bh, acc[nb], 0, 0, 0);
            acc[nb] = __builtin_amdgcn_mfma_f32_16x16x32_bf16(al, bh, acc[nb], 0, 0, 0);
            acc[nb] = __builtin_amdgcn_mfma_f32_16x16x32_bf16(ah, bl, acc[nb], 0, 0, 0);
        }
    }

#pragma unroll
    for (int nb = 0; nb < 4; nb++) {
        const int col = n0 + nb * 16 + lm;
        const float bv = bias[col];
#pragma unroll
        for (int r = 0; r < 4; r++) {
            const int row = m0 + wave * 16 + quad * 4 + r;
            C[(size_t)row * D_ + col] = acc[nb][r] + bv;
        }
    }
}

// ---------------------------------------------------------------------------
// MFMA flash attention (R9-verified): 128-row Q super-tile / 512 threads,
// per-wave causal skip, softmax-lite + deferred l-reduction, same-wave P
// round-trip; epilogue writes attn PRE-SPLIT into Q buffers.
// ---------------------------------------------------------------------------
#define PST 72   // u16 row stride (64 data + 8 pad)

__global__ __launch_bounds__(512, 4) void flash_attn_mfma(
    unsigned short* QAhi, unsigned short* QAlo,   // Q in, attn out (aliased)
    const unsigned short* __restrict__ Khi, const unsigned short* __restrict__ Klo,
    const unsigned short* __restrict__ vThi, const unsigned short* __restrict__ vTlo)
{
    __shared__ unsigned short KhiS[64 * PST];
    __shared__ unsigned short KloS[64 * PST];
    __shared__ unsigned short VhiS[64 * PST];   // V^T tile [d][s]
    __shared__ unsigned short VloS[64 * PST];
    __shared__ unsigned short PhS[128 * PST];
    __shared__ unsigned short PlS[128 * PST];

    const int t    = threadIdx.x;
    const int pj   = blockIdx.x;            // 0..7
    const int bh   = blockIdx.y;
    const int b    = bh >> 4, h = bh & 15;
    const int lane = t & 63, w = t >> 6;    // 8 waves
    const int lm   = lane & 15, quad = lane >> 4;

    const int srow = t >> 3;                // 0..63
    const int sseg = (t & 7) * 8;           // u16 col 0..56

    const unsigned short* Kh_b = Khi + (size_t)(b * S_) * D_ + h * HD + sseg;
    const unsigned short* Kl_b = Klo + (size_t)(b * S_) * D_ + h * HD + sseg;
    const unsigned short* Vh_b = vThi + ((size_t)((b * 16 + h) * 64 + srow)) * S_ + sseg;
    const unsigned short* Vl_b = vTlo + ((size_t)((b * 16 + h) * 64 + srow)) * S_ + sseg;

    for (int phse = 0; phse < 2; phse++) {
        const int qt = phse ? (15 - pj) : pj;
        const int q0 = qt * 128;
        const int ntiles = 2 * qt + 2;
        const int wdiag = (q0 >> 6) + (w >> 2);   // wave's diagonal k-tile

        short8 qh[2], ql[2];
        {
            const size_t qoff = (size_t)(b * S_ + q0 + 16 * w + lm) * D_ + h * HD + quad * 8;
            qh[0] = *(const short8*)&QAhi[qoff];
            qh[1] = *(const short8*)&QAhi[qoff + 32];
            ql[0] = *(const short8*)&QAlo[qoff];
            ql[1] = *(const short8*)&QAlo[qoff + 32];
        }

        float lsum[4] = {0.f, 0.f, 0.f, 0.f};
        floatx4 o[4];
#pragma unroll
        for (int nb = 0; nb < 4; nb++)
#pragma unroll
            for (int r = 0; r < 4; r++) o[nb][r] = 0.f;

        uint4 pkh, pkl, pvh, pvl;
        pkh = *(const uint4*)(Kh_b + (size_t)srow * D_);
        pkl = *(const uint4*)(Kl_b + (size_t)srow * D_);
        pvh = *(const uint4*)(Vh_b);
        pvl = *(const uint4*)(Vl_b);

        for (int kt = 0; kt < ntiles; kt++) {
            __syncthreads();
            *(uint4*)&KhiS[srow * PST + sseg] = pkh;
            *(uint4*)&KloS[srow * PST + sseg] = pkl;
            *(uint4*)&VhiS[srow * PST + sseg] = pvh;
            *(uint4*)&VloS[srow * PST + sseg] = pvl;
            __syncthreads();

            if (kt + 1 < ntiles) {
                const int k1 = (kt + 1) * 64;
                pkh = *(const uint4*)(Kh_b + (size_t)(k1 + srow) * D_);
                pkl = *(const uint4*)(Kl_b + (size_t)(k1 + srow) * D_);
                pvh = *(const uint4*)(Vh_b + k1);
                pvl = *(const uint4*)(Vl_b + k1);
            }

            if (kt <= wdiag) {
                floatx4 sa[4];
#pragma unroll
                for (int nb = 0; nb < 4; nb++)
#pragma unroll
                    for (int r = 0; r < 4; r++) sa[nb][r] = 0.f;
#pragma unroll
                for (int s = 0; s < 2; s++) {
#pragma unroll
                    for (int nb = 0; nb < 4; nb++) {
                        short8 kh = *(const short8*)&KhiS[(nb * 16 + lm) * PST + s * 32 + quad * 8];
                        short8 kl = *(const short8*)&KloS[(nb * 16 + lm) * PST + s * 32 + quad * 8];
                        sa[nb] = __builtin_amdgcn_mfma_f32_16x16x32_bf16(qh[s], kh, sa[nb], 0, 0, 0);
                        sa[nb] = __builtin_amdgcn_mfma_f32_16x16x32_bf16(ql[s], kh, sa[nb], 0, 0, 0);
                        sa[nb] = __builtin_amdgcn_mfma_f32_16x16x32_bf16(qh[s], kl, sa[nb], 0, 0, 0);
                    }
                }

                const bool diag = (kt == wdiag);
                const int kbase = kt * 64;
#pragma unroll
                for (int r = 0; r < 4; r++) {
                    const int qabs = q0 + 16 * w + 4 * quad + r;
                    const int rloc = 16 * w + 4 * quad + r;
#pragma unroll
                    for (int nb = 0; nb < 4; nb++) {
                        float p = __expf(sa[nb][r]);
                        if (diag && (kbase + 16 * nb + lm > qabs)) p = 0.f;
                        lsum[r] += p;
                        unsigned short hh, ll;
                        split2(p, hh, ll);
                        PhS[rloc * PST + 16 * nb + lm] = hh;
                        PlS[rloc * PST + 16 * nb + lm] = ll;
                    }
                }

#pragma unroll
                for (int ks = 0; ks < 2; ks++) {
                    short8 pf = *(const short8*)&PhS[(16 * w + lm) * PST + ks * 32 + quad * 8];
                    short8 pg = *(const short8*)&PlS[(16 * w + lm) * PST + ks * 32 + quad * 8];
#pragma unroll
                    for (int nb = 0; nb < 4; nb++) {
                        short8 vhf = *(const short8*)&VhiS[(16 * nb + lm) * PST + ks * 32 + quad * 8];
                        short8 vlf = *(const short8*)&VloS[(16 * nb + lm) * PST + ks * 32 + quad * 8];
                        o[nb] = __builtin_amdgcn_mfma_f32_16x16x32_bf16(pf, vhf, o[nb], 0, 0, 0);
                        o[nb] = __builtin_amdgcn_mfma_f32_16x16x32_bf16(pg, vhf, o[nb], 0, 0, 0);
                        o[nb] = __builtin_amdgcn_mfma_f32_16x16x32_bf16(pf, vlf, o[nb], 0, 0, 0);
                    }
                }
            }
        }

#pragma unroll
        for (int r = 0; r < 4; r++) {
            float l = lsum[r];
            l += __shfl_xor(l, 1);
            l += __shfl_xor(l, 2);
            l += __shfl_xor(l, 4);
            l += __shfl_xor(l, 8);
            const float inv = 1.f / l;
            const size_t rowoff =
                (size_t)(b * S_ + q0 + 16 * w + 4 * quad + r) * D_ + h * HD + lm;
#pragma unroll
            for (int nb = 0; nb < 4; nb++) {
                unsigned short hh, ll;
                split2(o[nb][r] * inv, hh, ll);
                QAhi[rowoff + 16 * nb] = hh;
                QAlo[rowoff + 16 * nb] = ll;
            }
        }
    }
}

// ---------------------------------------------------------------------------
extern "C" void kernel_launch(void* const* d_in, const int* in_sizes, int n_in,
                              void* d_out, int out_size, void* d_ws, size_t ws_size,
                              hipStream_t stream)
{
    const float* hs     = (const float*)d_in[0];
    const float* attn_w = (const float*)d_in[1];
    const float* attn_b = (const float*)d_in[2];
    const float* proj_w = (const float*)d_in[3];
    const float* proj_b = (const float*)d_in[4];
    float* outp = (float*)d_out;

    const size_t QE = (size_t)M_ * D_;          // 4,194,304
    const size_t WQ = (size_t)D_ * N_QKV;       // 3,145,728
    unsigned short* Qhi   = (unsigned short*)d_ws;       // also attn hi
    unsigned short* Qlo   = Qhi + QE;                    // also attn lo
    unsigned short* Khi   = Qlo + QE;
    unsigned short* Klo   = Khi + QE;
    unsigned short* vThi  = Klo + QE;
    unsigned short* vTlo  = vThi + QE;
    unsigned short* WqThi = vTlo + QE;
    unsigned short* WqTlo = WqThi + WQ;
    unsigned short* WpThi = WqTlo + WQ;
    unsigned short* WpTlo = WpThi + (size_t)D_ * D_;     // ws total = 64 MB

    // hs pre-split lives in d_out (scratch until gemm_out overwrites it):
    // [hsHi: QE u16 | hsLo: QE u16] = 16.78 MB = out_size*4 B exactly.
    unsigned short* hsHi = (unsigned short*)d_out;
    unsigned short* hsLo = hsHi + QE;

    dim3 blk(256);
    prep_hs<<<dim3(M_ * D_ / (256 * 8)), blk, 0, stream>>>(hs, hsHi, hsLo);
    prep_wT<<<dim3(N_QKV / 64, D_ / 64), blk, 0, stream>>>(attn_w, N_QKV, WqThi, WqTlo);
    prep_wT<<<dim3(D_ / 64, D_ / 64), blk, 0, stream>>>(proj_w, D_, WpThi, WpTlo);
    gemm_qkv<<<dim3(N_QKV / 128, M_ / 128), blk, 0, stream>>>(
        hsHi, hsLo, WqThi, WqTlo, attn_b, Qhi, Qlo, Khi, Klo, vThi, vTlo);
    flash_attn_mfma<<<dim3(8, B_ * H_), dim3(512), 0, stream>>>(
        Qhi, Qlo, Khi, Klo, vThi, vTlo);
    gemm_out<<<dim3(D_ / 64, M_ / 64), blk, 0, stream>>>(
        Qhi, Qlo, WpThi, WpTlo, proj_b, outp);
}